// Round 3
// baseline (1266.811 us; speedup 1.0000x reference)
//
#include <hip/hip_runtime.h>
#include <hip/hip_bf16.h>

typedef __bf16 bf16_t;
typedef __attribute__((ext_vector_type(8))) __bf16 bf16x8;
typedef __attribute__((ext_vector_type(4))) __bf16 bf16x4;
typedef __attribute__((ext_vector_type(4))) float f32x4;

#define GM 16384
#define GN 4096
#define GK 4096

// async global->LDS, 16B per lane; LDS dest is wave-uniform base + lane*16
#define GLOAD16(gp, lp)                                                        \
  __builtin_amdgcn_global_load_lds(                                            \
      (const __attribute__((address_space(1))) unsigned int*)(gp),             \
      (__attribute__((address_space(3))) unsigned int*)(lp), 16, 0, 0)

// ---------------------------------------------------------------------------
// Kernel 1: convert x (fp32) -> bf16, 16 elements (64B) per thread for ILP
// ---------------------------------------------------------------------------
__global__ __launch_bounds__(256) void cvt_x_kernel(
    const float* __restrict__ in, bf16_t* __restrict__ outb) {
  long i = (long)blockIdx.x * blockDim.x + threadIdx.x;
  const f32x4* v = (const f32x4*)in;
  f32x4 a = v[4 * i + 0];
  f32x4 b = v[4 * i + 1];
  f32x4 c = v[4 * i + 2];
  f32x4 d = v[4 * i + 3];
  bf16x8 r0, r1;
  r0[0] = (__bf16)a[0]; r0[1] = (__bf16)a[1]; r0[2] = (__bf16)a[2]; r0[3] = (__bf16)a[3];
  r0[4] = (__bf16)b[0]; r0[5] = (__bf16)b[1]; r0[6] = (__bf16)b[2]; r0[7] = (__bf16)b[3];
  r1[0] = (__bf16)c[0]; r1[1] = (__bf16)c[1]; r1[2] = (__bf16)c[2]; r1[3] = (__bf16)c[3];
  r1[4] = (__bf16)d[0]; r1[5] = (__bf16)d[1]; r1[6] = (__bf16)d[2]; r1[7] = (__bf16)d[3];
  ((bf16x8*)outb)[2 * i + 0] = r0;
  ((bf16x8*)outb)[2 * i + 1] = r1;
}

// ---------------------------------------------------------------------------
// Kernel 2: bpt[er][o] = probs[e] * B[e][o][r]
// thread t owns one o: reads 16 contiguous floats (coalesced 64B chunks),
// writes 16 coalesced stores (one per r, lanes -> consecutive o).
// grid 256: block = (e = bid>>4, o-block = bid&15 of 256)
// ---------------------------------------------------------------------------
__global__ __launch_bounds__(256) void make_bpt_kernel(
    const float* __restrict__ Bw, const float* __restrict__ probs,
    float* __restrict__ bpt) {
  int e = blockIdx.x >> 4;
  int o = ((blockIdx.x & 15) << 8) + threadIdx.x;
  float p = probs[e];
  const f32x4* src = (const f32x4*)(Bw + ((size_t)e << 16) + (size_t)o * 16);
  f32x4 v0 = src[0], v1 = src[1], v2 = src[2], v3 = src[3];
  float* dst = bpt + ((size_t)e * 16) * 4096 + o;
#pragma unroll
  for (int r = 0; r < 4; ++r) dst[r * 4096] = p * v0[r];
#pragma unroll
  for (int r = 0; r < 4; ++r) dst[(r + 4) * 4096] = p * v1[r];
#pragma unroll
  for (int r = 0; r < 4; ++r) dst[(r + 8) * 4096] = p * v2[r];
#pragma unroll
  for (int r = 0; r < 4; ++r) dst[(r + 12) * 4096] = p * v3[r];
}

// ---------------------------------------------------------------------------
// Kernel 3: weff[o][d] = bf16( W[o][d] + sum_er bpt[er][o] * A[er][d] )
// 128o x 64d tile, acc[4][8] per thread -> 32 FMA per 3 LDS b128 reads.
// tx = tid&7 (8 d-octets), ty = tid>>3 (32 o-quads).
// ---------------------------------------------------------------------------
__global__ __launch_bounds__(256) void weff_kernel(
    const float* __restrict__ W, const float* __restrict__ Aw,
    const float* __restrict__ bpt, bf16_t* __restrict__ weffp) {
  __shared__ __align__(16) float At[64 * 64];   // [er][d] 16KB
  __shared__ __align__(16) float Bt[64 * 128];  // [er][o] 32KB
  int tid = threadIdx.x;
  int d0 = (blockIdx.x & 63) << 6;   // 64 d-blocks
  int o0 = (blockIdx.x >> 6) << 7;   // 32 o-blocks
  int tx = tid & 7, ty = tid >> 3;

  float acc[4][8] = {};

  for (int kc = 0; kc < 256; kc += 64) {
    __syncthreads();
#pragma unroll
    for (int q = 0; q < 4; ++q) {  // At: 64 rows x 256B
      int er = (tid >> 4) + q * 16;
      *(f32x4*)&At[er * 64 + (tid & 15) * 4] =
          *(const f32x4*)&Aw[(size_t)(kc + er) * 4096 + d0 + (tid & 15) * 4];
    }
#pragma unroll
    for (int q = 0; q < 8; ++q) {  // Bt: 64 rows x 512B
      int er = (tid >> 5) + q * 8;
      *(f32x4*)&Bt[er * 128 + (tid & 31) * 4] =
          *(const f32x4*)&bpt[(size_t)(kc + er) * 4096 + o0 + (tid & 31) * 4];
    }
    __syncthreads();
#pragma unroll 4
    for (int kk = 0; kk < 64; ++kk) {
      f32x4 a0 = *(const f32x4*)&At[kk * 64 + tx * 8];
      f32x4 a1 = *(const f32x4*)&At[kk * 64 + tx * 8 + 4];
      f32x4 bv = *(const f32x4*)&Bt[kk * 128 + ty * 4];
#pragma unroll
      for (int i = 0; i < 4; ++i) {
#pragma unroll
        for (int j = 0; j < 4; ++j) {
          acc[i][j] = fmaf(bv[i], a0[j], acc[i][j]);
          acc[i][j + 4] = fmaf(bv[i], a1[j], acc[i][j + 4]);
        }
      }
    }
  }

#pragma unroll
  for (int i = 0; i < 4; ++i) {
    int o = o0 + ty * 4 + i;
    f32x4 w0 = *(const f32x4*)&W[(size_t)o * 4096 + d0 + tx * 8];
    f32x4 w1 = *(const f32x4*)&W[(size_t)o * 4096 + d0 + tx * 8 + 4];
    bf16x8 ov;
#pragma unroll
    for (int j = 0; j < 4; ++j) {
      ov[j] = (__bf16)(w0[j] + acc[i][j]);
      ov[j + 4] = (__bf16)(w1[j] + acc[i][j + 4]);
    }
    *(bf16x8*)&weffp[(size_t)o * 4096 + d0 + tx * 8] = ov;
  }
}

// ---------------------------------------------------------------------------
// Kernel 4: out[m][n] = sum_k xb[m][k]*weff[n][k] + bias[n]
// 128x128 tile, BK=32, DOUBLE-BUFFERED 2-phase pipeline (T3 minimum recipe):
//   per iter: stage tile t+1 into buf[cur^1]  (4x global_load_lds w16)
//             ds_read + 16 MFMA from buf[cur]
//             __syncthreads()  (= vmcnt(0)+lgkmcnt(0)+barrier)  -- ONE/iter
// Race-free: buf[cur^1] reads all completed before previous barrier; staged
// writes drained by vmcnt(0) before next iteration's ds_reads.
// XOR chunk swizzle keeps ds_read_b128 conflict-free with linear gload dest.
// ---------------------------------------------------------------------------
__global__ __launch_bounds__(256) void gemm_bt_bias_kernel(
    const bf16_t* __restrict__ xb, const bf16_t* __restrict__ weff,
    const float* __restrict__ bias, float* __restrict__ out) {
  __shared__ __align__(16) bf16_t As[2 * 128 * 32];  // 16KB dbuf
  __shared__ __align__(16) bf16_t Bs[2 * 128 * 32];  // 16KB dbuf

  int nwg = gridDim.x;          // 4096
  int cpx = nwg >> 3;           // 512
  int bid = blockIdx.x;
  int swz = (bid & 7) * cpx + (bid >> 3);  // bijective XCD swizzle (4096%8==0)
  int mt = swz >> 5;            // 128 m-tiles
  int nt = swz & 31;            // 32 n-tiles
  int blkM = mt << 7;
  int blkN = nt << 7;

  int tid = threadIdx.x;
  int lane = tid & 63;
  int wv = tid >> 6;            // wave 0..3
  int wr = wv >> 1, wc = wv & 1;

  // staging: wave wv covers rows [wv*32, wv*32+32) via 2 insts of 16 rows.
  // lane l -> row (l>>2), physical chunk (l&3); data chunk = (l&3)^((l>>3)&3)
  int srow = wv * 32 + (lane >> 2);
  int schunk = (lane & 3) ^ ((lane >> 3) & 3);
  const bf16_t* gA = xb + (long)(blkM + srow) * GK + schunk * 8;
  const bf16_t* gB = weff + (long)(blkN + srow) * GK + schunk * 8;
  int ldsOffA0 = (wv * 32) * 32;
  int ldsOffA1 = (wv * 32 + 16) * 32;

  // fragment read: row r = base + (lane&15), logical chunk c = lane>>4,
  // physical chunk = c ^ ((r>>1)&3) = (lane>>4) ^ ((lane>>1)&3)
  int r_l = lane & 15;
  int pcidx = (lane >> 4) ^ ((lane >> 1) & 3);

  f32x4 acc[4][4];
#pragma unroll
  for (int i = 0; i < 4; ++i)
#pragma unroll
    for (int j = 0; j < 4; ++j) acc[i][j] = (f32x4){0.f, 0.f, 0.f, 0.f};

  // prologue: stage tile 0 into buf 0
  GLOAD16(gA, As + ldsOffA0);
  GLOAD16(gA + 16 * GK, As + ldsOffA1);
  GLOAD16(gB, Bs + ldsOffA0);
  GLOAD16(gB + 16 * GK, Bs + ldsOffA1);
  __syncthreads();

  int cur = 0;
#define NT (GK / 32)
  for (int t = 0; t < NT; ++t) {
    // stage next tile into the other buffer (overlaps with this tile's MFMA)
    if (t + 1 < NT) {
      int kn = (t + 1) * 32;
      int nb = (cur ^ 1) * 4096;
      GLOAD16(gA + kn, As + nb + ldsOffA0);
      GLOAD16(gA + kn + 16 * GK, As + nb + ldsOffA1);
      GLOAD16(gB + kn, Bs + nb + ldsOffA0);
      GLOAD16(gB + kn + 16 * GK, Bs + nb + ldsOffA1);
      __builtin_amdgcn_sched_barrier(0);  // keep loads issued before compute
    }

    const bf16x8* AsV = (const bf16x8*)(As + cur * 4096);
    const bf16x8* BsV = (const bf16x8*)(Bs + cur * 4096);
    bf16x8 af[4], bfr[4];
#pragma unroll
    for (int mi = 0; mi < 4; ++mi)
      af[mi] = AsV[(wr * 64 + mi * 16 + r_l) * 4 + pcidx];
#pragma unroll
    for (int ni = 0; ni < 4; ++ni)
      bfr[ni] = BsV[(wc * 64 + ni * 16 + r_l) * 4 + pcidx];

#pragma unroll
    for (int mi = 0; mi < 4; ++mi)
#pragma unroll
      for (int ni = 0; ni < 4; ++ni)
        acc[mi][ni] = __builtin_amdgcn_mfma_f32_16x16x32_bf16(
            af[mi], bfr[ni], acc[mi][ni], 0, 0, 0);

    __syncthreads();  // vmcnt(0): staged tile ready; barrier: reads done
    cur ^= 1;
  }
#undef NT

  // epilogue: C/D layout col=lane&15, row=(lane>>4)*4+reg  (+bias)
  int n0 = blkN + wc * 64 + (lane & 15);
  int m0 = blkM + wr * 64 + ((lane >> 4) << 2);
#pragma unroll
  for (int ni = 0; ni < 4; ++ni) {
    float bv = bias[n0 + ni * 16];
#pragma unroll
    for (int mi = 0; mi < 4; ++mi) {
#pragma unroll
      for (int r = 0; r < 4; ++r) {
        out[(long)(m0 + mi * 16 + r) * GN + (n0 + ni * 16)] =
            acc[mi][ni][r] + bv;
      }
    }
  }
}

// ---------------------------------------------------------------------------
extern "C" void kernel_launch(void* const* d_in, const int* in_sizes, int n_in,
                              void* d_out, int out_size, void* d_ws,
                              size_t ws_size, hipStream_t stream) {
  const float* x = (const float*)d_in[0];      // [4,4096,4096]
  const float* W = (const float*)d_in[1];      // [4096,4096]
  const float* b = (const float*)d_in[2];      // [4096]
  const float* A = (const float*)d_in[3];      // [16,16,4096]
  const float* Bw = (const float*)d_in[4];     // [16,4096,16]
  const float* probs = (const float*)d_in[5];  // [16]
  float* out = (float*)d_out;

  // workspace layout:
  //   xb   : GM*GK bf16  = 128 MiB
  //   weff : GN*GK bf16  =  32 MiB
  //   bpt  : 256*GN f32  =   4 MiB
  size_t need = (size_t)GM * GK * 2 + (size_t)GN * GK * 2 + 256ull * GN * 4;
  if (ws_size < need) return;  // fail validation cleanly, never write OOB

  bf16_t* xb = (bf16_t*)d_ws;                    // 128 MiB
  bf16_t* weff = xb + (size_t)GM * GK;           // 32 MiB
  float* bpt = (float*)(weff + (size_t)GN * GK); // 4 MiB

  cvt_x_kernel<<<16384, 256, 0, stream>>>(x, xb);
  make_bpt_kernel<<<256, 256, 0, stream>>>(Bw, probs, bpt);
  weff_kernel<<<2048, 256, 0, stream>>>(W, A, bpt, weff);
  gemm_bt_bias_kernel<<<4096, 256, 0, stream>>>(xb, weff, b, out);
}